// Round 15
// baseline (994.720 us; speedup 1.0000x reference)
//
#include <hip/hip_runtime.h>
#include <hip/hip_bf16.h>

// ---------------- types ----------------
typedef unsigned short u16;
typedef u16   u16x4 __attribute__((ext_vector_type(4)));
typedef u16   u16x8 __attribute__((ext_vector_type(8)));
typedef short s16x8 __attribute__((ext_vector_type(8)));
typedef float f32x4 __attribute__((ext_vector_type(4)));

// Problem constants
#define NB   64
#define NL   512
#define ND   512
#define NA   8
#define K2   1024        // 2*D (original concat K)
#define KH   512         // GEMM K after user-split (H part only)
#define MROWS 32768      // B*L

__device__ __forceinline__ float b2f(u16 u) {
    unsigned int x = ((unsigned int)u) << 16;
    return __uint_as_float(x);
}
__device__ __forceinline__ u16 f2b(float f) {
    unsigned int x = __float_as_uint(f);
    unsigned int r = (x + 0x7fffu + ((x >> 16) & 1u)) >> 16;
    return (u16)r;
}

// permuted column position for original k within a 64-col K-block (16x16x32 frag)
__device__ __forceinline__ int permc(int k) {
    int ks  = k >> 6;
    int kr  = k & 63;
    int kk  = kr >> 5;
    int k32 = kr & 31;
    int h   = k32 >> 4;
    int rem = k32 & 15;
    int g   = rem >> 2;
    int e0  = rem & 3;
    return ks * 64 + kk * 32 + g * 8 + h * 4 + e0;
}

__device__ __forceinline__ void gload16(const u16* g, u16* l) {
    __builtin_amdgcn_global_load_lds(
        (const __attribute__((address_space(1))) unsigned int*)g,
        (__attribute__((address_space(3))) unsigned int*)l, 16, 0, 0);
}

// ---------------- kernel 1: fused prep (build_batch + build_wt + user_mm) ----------------
#define PREP_BB 4096
#define PREP_WT 2048
#define PREP_UM 512

__global__ __launch_bounds__(256) void prep_k(
    const float* __restrict__ H, u16* __restrict__ Bt,
    const float* __restrict__ Wmf, const float* __restrict__ Wpf,
    u16* __restrict__ Wm, u16* __restrict__ Wp,
    const float* __restrict__ U, float* __restrict__ uM, float* __restrict__ uP) {
    __shared__ float shp[5120];     // 20 KB union
    int bid = blockIdx.x;
    int t = threadIdx.x;

    if (bid < PREP_BB) {
        // ---- build_batch ----
        size_t stride = (size_t)PREP_BB * 256;
        for (size_t idx = (size_t)bid * 256 + t; idx < (size_t)MROWS * 128; idx += stride) {
            int r  = (int)(idx >> 7);
            int c  = ((int)idx & 127) << 2;       // permuted col (multiple of 4)
            int ks = c >> 6;
            int w64 = c & 63;
            int cq = w64 >> 3;
            int h  = (w64 >> 2) & 1;
            int kbase = ks * 64 + (cq >> 2) * 32 + (cq & 3) * 4 + h * 16;  // < 512
            f32x4 v = *(const f32x4*)(H + (size_t)r * ND + kbase);
            u16x4 o;
            o[0] = f2b(v[0]); o[1] = f2b(v[1]); o[2] = f2b(v[2]); o[3] = f2b(v[3]);
            *(u16x4*)(Bt + (size_t)r * KH + c) = o;
        }
    } else if (bid < PREP_BB + PREP_WT) {
        // ---- build_wt ----
        int b2 = bid - PREP_BB;
        float (*ld)[65] = (float(*)[65])shp;
        int kt  = b2 & 15;
        int dt  = (b2 >> 4) & 7;
        int a   = (b2 >> 7) & 7;
        int mat = b2 >> 10;
        const float* W = mat ? Wpf : Wmf;
        u16* Wt = mat ? Wp : Wm;
        int k0 = kt * 32, d0 = dt * 64;
        #pragma unroll
        for (int it = 0; it < 8; ++it) {
            int lin = it * 256 + t;
            int i = lin >> 6, j = lin & 63;
            ld[i][j] = W[((size_t)a * K2 + k0 + i) * ND + d0 + j];
        }
        __syncthreads();
        #pragma unroll
        for (int it = 0; it < 8; ++it) {
            int lin = it * 256 + t;
            int dl = lin >> 5, kl = lin & 31;
            int k = k0 + kl;
            Wt[((size_t)a * ND + d0 + dl) * KH + permc(k)] = f2b(ld[kl][dl]);
        }
    } else {
        // ---- user_mm: block = (a, mat, cg of 64 cols, bs of 16 batches) ----
        int b2 = bid - PREP_BB - PREP_WT;
        int a   = b2 & 7;
        int mat = (b2 >> 3) & 1;
        int cg  = (b2 >> 4) & 7;
        int bs  = b2 >> 7;               // 0..3
        const float* W = mat ? Wpf : Wmf;
        float* uX = mat ? uP : uM;
        float* ul = shp;                 // [16][64]
        float* wl = shp + 1024;          // [64][64]
        int c = t & 63, bq = t >> 6;     // col, batch-quarter (wave-uniform)

        float acc[4] = {0.0f, 0.0f, 0.0f, 0.0f};
        for (int kt = 0; kt < 8; ++kt) {
            __syncthreads();
            #pragma unroll
            for (int it = 0; it < 16; ++it) {
                int idx = it * 256 + t;
                wl[idx] = W[((size_t)a * K2 + 512 + kt * 64 + (idx >> 6)) * ND + cg * 64 + (idx & 63)];
            }
            #pragma unroll
            for (int it = 0; it < 4; ++it) {
                int idx = it * 256 + t;
                ul[idx] = U[(size_t)(bs * 16 + (idx >> 6)) * ND + kt * 64 + (idx & 63)];
            }
            __syncthreads();
            #pragma unroll
            for (int k4 = 0; k4 < 16; ++k4) {
                f32x4 uv[4];
                #pragma unroll
                for (int bi = 0; bi < 4; ++bi)
                    uv[bi] = *(const f32x4*)&ul[(bq * 4 + bi) * 64 + k4 * 4];  // broadcast read
                #pragma unroll
                for (int e = 0; e < 4; ++e) {
                    float wv = wl[(k4 * 4 + e) * 64 + c];                      // conflict-free
                    #pragma unroll
                    for (int bi = 0; bi < 4; ++bi)
                        acc[bi] += uv[bi][e] * wv;
                }
            }
        }
        #pragma unroll
        for (int bi = 0; bi < 4; ++bi)
            uX[((size_t)a * NB + bs * 16 + bq * 4 + bi) * ND + cg * 64 + c] = acc[bi];
    }
}

// ---------------- kernel 3: 128x128-tile K=512 dual GEMM, BK=64, 2 blocks/CU ----------------
// 8 waves (2M x 4N, wave 64x32). A double-buffered (2x16KB), Bm/Bp single (16KB each).
// 128B LDS rows -> conflict-free 8-slot swizzle. 8 K-steps.
#define BAR()    do { __builtin_amdgcn_sched_barrier(0); \
                      __builtin_amdgcn_s_barrier(); \
                      __builtin_amdgcn_sched_barrier(0); } while (0)
#define WAITV(n) do { asm volatile("s_waitcnt vmcnt(" #n ")" ::: "memory"); \
                      __builtin_amdgcn_sched_barrier(0); } while (0)
#define LGKM0()  do { asm volatile("s_waitcnt lgkmcnt(0)" ::: "memory"); \
                      __builtin_amdgcn_sched_barrier(0); } while (0)
#define PRIO1    __builtin_amdgcn_s_setprio(1);
#define PRIO0    __builtin_amdgcn_s_setprio(0);

// LDS pool (u16 units): A 2x8192 @0, Bm 8192 @16384, Bp 8192 @24576. 64KB total.
#define A_OFF  0
#define M_OFF  16384
#define P_OFF  24576
#define TST    136      // epilogue tile row stride (u16), 128x136 = 34KB

#define RDA(B_) { _Pragma("unroll") for (int i_ = 0; i_ < 4; ++i_) { \
    af[i_ * 2 + 0] = *(const s16x8*)(pA0 + (B_) * 8192 + i_ * 1024); \
    af[i_ * 2 + 1] = *(const s16x8*)(pA1 + (B_) * 8192 + i_ * 1024); } }
#define RDB() { \
    fm[0] = *(const s16x8*)(pM0); fm[1] = *(const s16x8*)(pM1); \
    fm[2] = *(const s16x8*)(pM0 + 1024); fm[3] = *(const s16x8*)(pM1 + 1024); \
    fp[0] = *(const s16x8*)(pP0); fp[1] = *(const s16x8*)(pP1); \
    fp[2] = *(const s16x8*)(pP0 + 1024); fp[3] = *(const s16x8*)(pP1 + 1024); }

#define MMA_M { _Pragma("unroll") for (int kk_ = 0; kk_ < 2; ++kk_) \
    _Pragma("unroll") for (int i_ = 0; i_ < 4; ++i_) \
    _Pragma("unroll") for (int j_ = 0; j_ < 2; ++j_) \
        accM[i_][j_] = __builtin_amdgcn_mfma_f32_16x16x32_bf16( \
            af[i_ * 2 + kk_], fm[j_ * 2 + kk_], accM[i_][j_], 0, 0, 0); }
#define MMA_P { _Pragma("unroll") for (int kk_ = 0; kk_ < 2; ++kk_) \
    _Pragma("unroll") for (int i_ = 0; i_ < 4; ++i_) \
    _Pragma("unroll") for (int j_ = 0; j_ < 2; ++j_) \
        accP[i_][j_] = __builtin_amdgcn_mfma_f32_16x16x32_bf16( \
            af[i_ * 2 + kk_], fp[j_ * 2 + kk_], accP[i_][j_], 0, 0, 0); }

// K-step: stage A(t+1) early; read 16 frags; drain lgkm; barrier; stage B(t+1);
// MFMA under in-flight DMA; drain vmcnt; barrier.
#define STEP(CUR, T) { \
    stA((CUR) ^ 1, (T) + 1); \
    RDA(CUR) RDB() \
    LGKM0(); BAR(); \
    stM((T) + 1); stP((T) + 1); \
    PRIO1 MMA_M PRIO0 \
    PRIO1 MMA_P PRIO0 \
    WAITV(0); BAR(); }

__global__ __launch_bounds__(512, 4) void gemm8_k(
    const u16* __restrict__ Bt, const u16* __restrict__ Wm, const u16* __restrict__ Wp,
    const float* __restrict__ bm, const float* __restrict__ bp,
    const float* __restrict__ uM, const float* __restrict__ uP,
    const float* __restrict__ asp,
    u16* __restrict__ item, float* __restrict__ scorep,
    int a0, int log2na, int nwg) {
    __shared__ u16 smem[32768];         // 64 KB pool

    int bid = blockIdx.x;
    int chunk = nwg >> 3;                       // XCD-aware swizzle (nwg % 8 == 0)
    int b = (bid & 7) * chunk + (bid >> 3);
    int nt = b & 3;                             // N-tile fastest: share A panel
    int al = (b >> 2) & ((1 << log2na) - 1);
    int mt = b >> (2 + log2na);                 // 0..255
    int a  = a0 + al;

    int tid = threadIdx.x;
    int lane = tid & 63;
    int w  = tid >> 6;        // 0..7
    int wr = w >> 2;          // 0..1  (M half: 64 rows)
    int wc = w & 3;           // 0..3  (N quarter: 32 cols)
    int g = lane >> 4, r15 = lane & 15;

    const u16* Abase = Bt + (size_t)(mt * 128) * KH;
    const u16* Mbase = Wm + ((size_t)a * ND + nt * 128) * KH;
    const u16* Pbase = Wp + ((size_t)a * ND + nt * 128) * KH;

    // hoisted swizzled read bases: slot = (kk*4+g) ^ (row&7), loop-invariant
    int s0 = g ^ (r15 & 7);
    int s1 = (4 + g) ^ (r15 & 7);
    const u16* pA0 = &smem[A_OFF + (wr * 64 + r15) * 64 + s0 * 8];
    const u16* pA1 = &smem[A_OFF + (wr * 64 + r15) * 64 + s1 * 8];
    const u16* pM0 = &smem[M_OFF + (wc * 32 + r15) * 64 + s0 * 8];
    const u16* pM1 = &smem[M_OFF + (wc * 32 + r15) * 64 + s1 * 8];
    const u16* pP0 = &smem[P_OFF + (wc * 32 + r15) * 64 + s0 * 8];
    const u16* pP1 = &smem[P_OFF + (wc * 32 + r15) * 64 + s1 * 8];

    // staging: linear LDS dest, inverse-swizzled global source. 2 rounds/tile.
    int srow = tid >> 3, sq = tid & 7;
    int qsw = sq ^ (srow & 7);                  // (rnd*64+srow)&7 == srow&7
    auto stA = [&](int buf, int ks) {
        #pragma unroll
        for (int rnd = 0; rnd < 2; ++rnd) {
            int row = rnd * 64 + srow;
            gload16(Abase + (size_t)row * KH + ks * 64 + qsw * 8,
                    &smem[A_OFF + buf * 8192 + row * 64 + sq * 8]);
        }
    };
    auto stM = [&](int ks) {
        #pragma unroll
        for (int rnd = 0; rnd < 2; ++rnd) {
            int row = rnd * 64 + srow;
            gload16(Mbase + (size_t)row * KH + ks * 64 + qsw * 8,
                    &smem[M_OFF + row * 64 + sq * 8]);
        }
    };
    auto stP = [&](int ks) {
        #pragma unroll
        for (int rnd = 0; rnd < 2; ++rnd) {
            int row = rnd * 64 + srow;
            gload16(Pbase + (size_t)row * KH + ks * 64 + qsw * 8,
                    &smem[P_OFF + row * 64 + sq * 8]);
        }
    };

    f32x4 accM[4][2], accP[4][2];
    #pragma unroll
    for (int i = 0; i < 4; ++i)
        #pragma unroll
        for (int j = 0; j < 2; ++j) { accM[i][j] = 0.0f; accP[i][j] = 0.0f; }

    s16x8 af[8], fm[4], fp[4];

    // ---- prologue: stage K0 ----
    stA(0, 0); stM(0); stP(0);
    WAITV(0); BAR();

    // ---- steady loop: K-steps 0..6 (8 total, BK=64) ----
    for (int t = 0; t < 6; t += 2) {
        STEP(0, t)
        STEP(1, t + 1)
    }
    STEP(0, 6)      // stages ks=7 (A into buf1, B overwrite)

    // ---- K-step 7: compute only (cur = 1) ----
    {
        RDA(1) RDB()
        PRIO1 MMA_M PRIO0
        PRIO1 MMA_P PRIO0
    }

    // ---- epilogue phase 1: bias + user fold + fast sigmoid -> LDS tile ----
    BAR();   // all frag reads consumed by MFMA (compiler-drained); reuse pool as [128][TST]
    {
        int gc0 = nt * 128 + wc * 32 + r15;
        int gc1 = gc0 + 16;
        int bix = mt >> 2;                  // 4 blocks of 128 rows per batch
        size_t ub = ((size_t)a * NB + bix) * ND;
        float bmv0 = bm[a * ND + gc0] + uM[ub + gc0];
        float bmv1 = bm[a * ND + gc1] + uM[ub + gc1];
        float bpv0 = bp[a * ND + gc0] + uP[ub + gc0];
        float bpv1 = bp[a * ND + gc1] + uP[ub + gc1];
        int col0 = wc * 32 + r15;
        #pragma unroll
        for (int i = 0; i < 4; ++i) {
            int row0 = wr * 64 + i * 16 + g * 4;
            #pragma unroll
            for (int jj = 0; jj < 4; ++jj) {
                float m0 = accM[i][0][jj] + bmv0;
                float p0 = accP[i][0][jj] + bpv0;
                float v0 = p0 * __builtin_amdgcn_rcpf(1.0f + __expf(-m0));
                float m1 = accM[i][1][jj] + bmv1;
                float p1 = accP[i][1][jj] + bpv1;
                float v1 = p1 * __builtin_amdgcn_rcpf(1.0f + __expf(-m1));
                unsigned int pk;
                asm("v_cvt_pk_bf16_f32 %0, %1, %2" : "=v"(pk) : "v"(v0), "v"(v1));
                smem[(row0 + jj) * TST + col0]      = (u16)pk;
                smem[(row0 + jj) * TST + col0 + 16] = (u16)(pk >> 16);
            }
        }
    }
    BAR();
    // ---- epilogue phase 2: coalesced item store + fused score partials ----
    {
        #pragma unroll
        for (int q = 0; q < 4; ++q) {
            int cid = q * 512 + tid;            // 128 rows x 16 chunks
            int row_l = cid >> 4;
            int c8 = (cid & 15) << 3;
            u16x8 tv = *(const u16x8*)&smem[row_l * TST + c8];
            int rowg = mt * 128 + row_l;
            int a2 = rowg & 7;
            int colg8 = nt * 128 + c8;
            f32x4 w0 = *(const f32x4*)&asp[a2 * ND + colg8];
            f32x4 w1 = *(const f32x4*)&asp[a2 * ND + colg8 + 4];
            float s = b2f(tv[0]) * w0[0] + b2f(tv[1]) * w0[1]
                    + b2f(tv[2]) * w0[2] + b2f(tv[3]) * w0[3]
                    + b2f(tv[4]) * w1[0] + b2f(tv[5]) * w1[1]
                    + b2f(tv[6]) * w1[2] + b2f(tv[7]) * w1[3];
            *(u16x8*)(item + ((size_t)al * MROWS + rowg) * ND + colg8) = tv;
            s += __shfl_xor(s, 1);
            s += __shfl_xor(s, 2);
            s += __shfl_xor(s, 4);
            s += __shfl_xor(s, 8);
            if ((tid & 15) == 0)
                scorep[((size_t)al * MROWS + rowg) * 4 + nt] = s;
        }
    }
}

// ---------------- kernel 4: softmax(L) + weighted sum, D-split x8 ----------------
__global__ __launch_bounds__(512) void attn_out_k(
    const u16* __restrict__ item, const float* __restrict__ scorep,
    float* __restrict__ out, int b0) {
    __shared__ float attn[512];
    __shared__ float red[512];
    int t = threadIdx.x;
    int ds = blockIdx.x & 7;              // D slice (64 cols)
    int ap = (blockIdx.x >> 3) & 7;       // aspect slot
    int bl = blockIdx.x >> 6;             // local batch
    int bg = b0 + bl;

    size_t R = (size_t)bl * 4096 + (size_t)t * 8 + ap;
    f32x4 q = *(const f32x4*)(scorep + R * 4);
    float s = (q[0] + q[1]) + (q[2] + q[3]);

    red[t] = s;
    __syncthreads();
    for (int off = 256; off > 0; off >>= 1) {
        if (t < off) red[t] = fmaxf(red[t], red[t + off]);
        __syncthreads();
    }
    float mx = red[0];
    __syncthreads();
    float p = __expf(s - mx);
    red[t] = p;
    __syncthreads();
    for (int off = 256; off > 0; off >>= 1) {
        if (t < off) red[t] += red[t + off];
        __syncthreads();
    }
    float inv = 1.0f / red[0];
    attn[t] = p * inv;
    __syncthreads();

    int lg = t >> 6, c = t & 63;
    const u16* base = item + ((size_t)bl * 4096 + ap) * ND + ds * 64 + c;
    float acc = 0.0f;
    #pragma unroll 4
    for (int l = lg; l < 512; l += 8)
        acc += attn[l] * b2f(base[(size_t)l * 8 * ND]);
    red[t] = acc;
    __syncthreads();
    if (t < 64) {
        float o = 0.0f;
        #pragma unroll
        for (int k = 0; k < 8; ++k) o += red[k * 64 + t];
        out[((size_t)bg * NA + ap) * ND + ds * 64 + t] = o;
    }
}

// ---------------- launcher ----------------
extern "C" void kernel_launch(void* const* d_in, const int* in_sizes, int n_in,
                              void* d_out, int out_size, void* d_ws, size_t ws_size,
                              hipStream_t stream) {
    const float* H   = (const float*)d_in[0];
    const float* U   = (const float*)d_in[1];
    const float* asp = (const float*)d_in[2];
    const float* Wmf = (const float*)d_in[3];
    const float* bmf = (const float*)d_in[4];
    const float* Wpf = (const float*)d_in[5];
    const float* bpf = (const float*)d_in[6];
    float* out = (float*)d_out;

    char* ws = (char*)d_ws;
    const size_t BT_BYTES = (size_t)MROWS * KH * 2;            // 32 MB
    const size_t WT_BYTES = (size_t)NA * ND * KH * 2;          // 4 MB each
    const size_t U_BYTES  = (size_t)NA * NB * ND * 4;          // 1 MB each
    u16*   Bt = (u16*)(ws);
    u16*   Wm = (u16*)(ws + BT_BYTES);
    u16*   Wp = (u16*)(ws + BT_BYTES + WT_BYTES);
    float* uM = (float*)(ws + BT_BYTES + 2 * WT_BYTES);
    float* uP = (float*)(ws + BT_BYTES + 2 * WT_BYTES + U_BYTES);
    size_t fixed = BT_BYTES + 2 * WT_BYTES + 2 * U_BYTES;      // 42 MB
    const size_t ITEM_PER_ASPECT  = (size_t)MROWS * ND * 2;    // 32 MB
    const size_t SCORE_PER_ASPECT = (size_t)MROWS * 4 * 4;     // 512 KB
    size_t avail = (ws_size > fixed) ? (ws_size - fixed) : 0;
    int na = (int)(avail / (ITEM_PER_ASPECT + SCORE_PER_ASPECT));
    if (na > NA) na = NA;
    if (na < 1) na = 1;
    int log2na = 0;
    while ((2 << log2na) <= na) ++log2na;
    na = 1 << log2na;
    u16*   item   = (u16*)(ws + fixed);
    float* scorep = (float*)(ws + fixed + (size_t)na * ITEM_PER_ASPECT);

    prep_k<<<PREP_BB + PREP_WT + PREP_UM, 256, 0, stream>>>(
        H, Bt, Wmf, Wpf, Wm, Wp, U, uM, uP);

    for (int a0 = 0; a0 < NA; a0 += na) {
        int n = (na < NA - a0) ? na : (NA - a0);
        gemm8_k<<<n * 1024, 512, 0, stream>>>(Bt, Wm, Wp, bmf, bpf, uM, uP, asp,
                                              item, scorep, a0, log2na, n * 1024);
        attn_out_k<<<n * 512, 512, 0, stream>>>(item, scorep, out, a0 * 8);
    }
}

// Round 16
// 422.166 us; speedup vs baseline: 2.3562x; 2.3562x over previous
//
#include <hip/hip_runtime.h>
#include <hip/hip_bf16.h>

// ---------------- types ----------------
typedef unsigned short u16;
typedef u16   u16x4 __attribute__((ext_vector_type(4)));
typedef u16   u16x8 __attribute__((ext_vector_type(8)));
typedef short s16x8 __attribute__((ext_vector_type(8)));
typedef float f32x4 __attribute__((ext_vector_type(4)));

// Problem constants
#define NB   64
#define NL   512
#define ND   512
#define NA   8
#define K2   1024        // 2*D (original concat K)
#define KH   512         // GEMM K after user-split (H part only)
#define MROWS 32768      // B*L

__device__ __forceinline__ float b2f(u16 u) {
    unsigned int x = ((unsigned int)u) << 16;
    return __uint_as_float(x);
}
__device__ __forceinline__ u16 f2b(float f) {
    unsigned int x = __float_as_uint(f);
    unsigned int r = (x + 0x7fffu + ((x >> 16) & 1u)) >> 16;
    return (u16)r;
}

// permuted column position for original k within a 64-col K-block (16x16x32 frag)
__device__ __forceinline__ int permc(int k) {
    int ks  = k >> 6;
    int kr  = k & 63;
    int kk  = kr >> 5;
    int k32 = kr & 31;
    int h   = k32 >> 4;
    int rem = k32 & 15;
    int g   = rem >> 2;
    int e0  = rem & 3;
    return ks * 64 + kk * 32 + g * 8 + h * 4 + e0;
}

__device__ __forceinline__ void gload16(const u16* g, u16* l) {
    __builtin_amdgcn_global_load_lds(
        (const __attribute__((address_space(1))) unsigned int*)g,
        (__attribute__((address_space(3))) unsigned int*)l, 16, 0, 0);
}

// ---------------- kernel 1: fused prep (build_batch + build_wt + user_mm) ----------------
#define PREP_BB 4096
#define PREP_WT 2048
#define PREP_UM 512

__global__ __launch_bounds__(256) void prep_k(
    const float* __restrict__ H, u16* __restrict__ Bt,
    const float* __restrict__ Wmf, const float* __restrict__ Wpf,
    u16* __restrict__ Wm, u16* __restrict__ Wp,
    const float* __restrict__ U, float* __restrict__ uM, float* __restrict__ uP) {
    __shared__ float shp[5120];     // 20 KB union
    int bid = blockIdx.x;
    int t = threadIdx.x;

    if (bid < PREP_BB) {
        // ---- build_batch ----
        size_t stride = (size_t)PREP_BB * 256;
        for (size_t idx = (size_t)bid * 256 + t; idx < (size_t)MROWS * 128; idx += stride) {
            int r  = (int)(idx >> 7);
            int c  = ((int)idx & 127) << 2;       // permuted col (multiple of 4)
            int ks = c >> 6;
            int w64 = c & 63;
            int cq = w64 >> 3;
            int h  = (w64 >> 2) & 1;
            int kbase = ks * 64 + (cq >> 2) * 32 + (cq & 3) * 4 + h * 16;  // < 512
            f32x4 v = *(const f32x4*)(H + (size_t)r * ND + kbase);
            u16x4 o;
            o[0] = f2b(v[0]); o[1] = f2b(v[1]); o[2] = f2b(v[2]); o[3] = f2b(v[3]);
            *(u16x4*)(Bt + (size_t)r * KH + c) = o;
        }
    } else if (bid < PREP_BB + PREP_WT) {
        // ---- build_wt ----
        int b2 = bid - PREP_BB;
        float (*ld)[65] = (float(*)[65])shp;
        int kt  = b2 & 15;
        int dt  = (b2 >> 4) & 7;
        int a   = (b2 >> 7) & 7;
        int mat = b2 >> 10;
        const float* W = mat ? Wpf : Wmf;
        u16* Wt = mat ? Wp : Wm;
        int k0 = kt * 32, d0 = dt * 64;
        #pragma unroll
        for (int it = 0; it < 8; ++it) {
            int lin = it * 256 + t;
            int i = lin >> 6, j = lin & 63;
            ld[i][j] = W[((size_t)a * K2 + k0 + i) * ND + d0 + j];
        }
        __syncthreads();
        #pragma unroll
        for (int it = 0; it < 8; ++it) {
            int lin = it * 256 + t;
            int dl = lin >> 5, kl = lin & 31;
            int k = k0 + kl;
            Wt[((size_t)a * ND + d0 + dl) * KH + permc(k)] = f2b(ld[kl][dl]);
        }
    } else {
        // ---- user_mm: block = (a, mat, cg of 64 cols, bs of 16 batches) ----
        int b2 = bid - PREP_BB - PREP_WT;
        int a   = b2 & 7;
        int mat = (b2 >> 3) & 1;
        int cg  = (b2 >> 4) & 7;
        int bs  = b2 >> 7;               // 0..3
        const float* W = mat ? Wpf : Wmf;
        float* uX = mat ? uP : uM;
        float* ul = shp;                 // [16][64]
        float* wl = shp + 1024;          // [64][64]
        int c = t & 63, bq = t >> 6;     // col, batch-quarter (wave-uniform)

        float acc[4] = {0.0f, 0.0f, 0.0f, 0.0f};
        for (int kt = 0; kt < 8; ++kt) {
            __syncthreads();
            #pragma unroll
            for (int it = 0; it < 16; ++it) {
                int idx = it * 256 + t;
                wl[idx] = W[((size_t)a * K2 + 512 + kt * 64 + (idx >> 6)) * ND + cg * 64 + (idx & 63)];
            }
            #pragma unroll
            for (int it = 0; it < 4; ++it) {
                int idx = it * 256 + t;
                ul[idx] = U[(size_t)(bs * 16 + (idx >> 6)) * ND + kt * 64 + (idx & 63)];
            }
            __syncthreads();
            #pragma unroll
            for (int k4 = 0; k4 < 16; ++k4) {
                f32x4 uv[4];
                #pragma unroll
                for (int bi = 0; bi < 4; ++bi)
                    uv[bi] = *(const f32x4*)&ul[(bq * 4 + bi) * 64 + k4 * 4];  // broadcast read
                #pragma unroll
                for (int e = 0; e < 4; ++e) {
                    float wv = wl[(k4 * 4 + e) * 64 + c];                      // conflict-free
                    #pragma unroll
                    for (int bi = 0; bi < 4; ++bi)
                        acc[bi] += uv[bi][e] * wv;
                }
            }
        }
        #pragma unroll
        for (int bi = 0; bi < 4; ++bi)
            uX[((size_t)a * NB + bs * 16 + bq * 4 + bi) * ND + cg * 64 + c] = acc[bi];
    }
}

// ---------------- kernel 3: 128x128-tile K=512 dual GEMM, 2 blocks/CU ----------------
// BM=128, BN=128, BK=32, 8 waves (2M x 4N, wave 64x32), double-buffered LDS 48KB.
// (R14-exact configuration: 167 us/dispatch, VGPR 64, no spill.)
#define BAR()    do { __builtin_amdgcn_sched_barrier(0); \
                      __builtin_amdgcn_s_barrier(); \
                      __builtin_amdgcn_sched_barrier(0); } while (0)
#define WAITV(n) do { asm volatile("s_waitcnt vmcnt(" #n ")" ::: "memory"); \
                      __builtin_amdgcn_sched_barrier(0); } while (0)
#define PRIO1    __builtin_amdgcn_s_setprio(1);
#define PRIO0    __builtin_amdgcn_s_setprio(0);

// LDS pool (u16 units): A 2x4096 @0, Bm 2x4096 @8192, Bp 2x4096 @16384.
#define A_OFF  0
#define M_OFF  8192
#define P_OFF  16384
#define TST    136      // epilogue tile row stride (u16), 128x136 = 34KB

#define RDA(B_) { _Pragma("unroll") for (int i_ = 0; i_ < 4; ++i_) \
    af[i_] = *(const s16x8*)(pA + (B_) * 4096 + i_ * 512); }
#define RDM(B_) { fm[0] = *(const s16x8*)(pM + (B_) * 4096); \
                  fm[1] = *(const s16x8*)(pM + (B_) * 4096 + 512); }
#define RDP(B_) { fp[0] = *(const s16x8*)(pP + (B_) * 4096); \
                  fp[1] = *(const s16x8*)(pP + (B_) * 4096 + 512); }

#define MMAM { _Pragma("unroll") for (int i_ = 0; i_ < 4; ++i_) \
    _Pragma("unroll") for (int j_ = 0; j_ < 2; ++j_) \
        accM[i_][j_] = __builtin_amdgcn_mfma_f32_16x16x32_bf16( \
            af[i_], fm[j_], accM[i_][j_], 0, 0, 0); }
#define MMAP { _Pragma("unroll") for (int i_ = 0; i_ < 4; ++i_) \
    _Pragma("unroll") for (int j_ = 0; j_ < 2; ++j_) \
        accP[i_][j_] = __builtin_amdgcn_mfma_f32_16x16x32_bf16( \
            af[i_], fp[j_], accP[i_][j_], 0, 0, 0); }

#define STEP(CUR, T) { \
    stA((CUR) ^ 1, (T) + 1); stM((CUR) ^ 1, (T) + 1); stP((CUR) ^ 1, (T) + 1); \
    RDA(CUR) RDM(CUR) \
    PRIO1 MMAM PRIO0 \
    RDP(CUR) \
    PRIO1 MMAP PRIO0 \
    WAITV(0); BAR(); }

__global__ __launch_bounds__(512, 4) void gemm8_k(
    const u16* __restrict__ Bt, const u16* __restrict__ Wm, const u16* __restrict__ Wp,
    const float* __restrict__ bm, const float* __restrict__ bp,
    const float* __restrict__ uM, const float* __restrict__ uP,
    const float* __restrict__ asp,
    u16* __restrict__ item, float* __restrict__ scorep,
    int a0, int log2na, int nwg) {
    __shared__ u16 smem[24576];         // 48 KB pool

    int bid = blockIdx.x;
    int chunk = nwg >> 3;                       // XCD-aware swizzle (nwg % 8 == 0)
    int b = (bid & 7) * chunk + (bid >> 3);
    int nt = b & 3;                             // N-tile fastest: share A panel
    int al = (b >> 2) & ((1 << log2na) - 1);
    int mt = b >> (2 + log2na);                 // 0..255
    int a  = a0 + al;

    int tid = threadIdx.x;
    int lane = tid & 63;
    int w  = tid >> 6;        // 0..7
    int wr = w >> 2;          // 0..1  (M half: 64 rows)
    int wc = w & 3;           // 0..3  (N quarter: 32 cols)
    int g = lane >> 4, r15 = lane & 15;

    const u16* Abase = Bt + (size_t)(mt * 128) * KH;
    const u16* Mbase = Wm + ((size_t)a * ND + nt * 128) * KH;
    const u16* Pbase = Wp + ((size_t)a * ND + nt * 128) * KH;

    // hoisted swizzled read bases: slot = g ^ (row&3) ^ ((row>>2)&3), loop-invariant
    int ps = (g ^ (r15 & 3) ^ ((r15 >> 2) & 3)) << 3;
    const u16* pA = &smem[A_OFF + (wr * 64 + r15) * 32 + ps];
    const u16* pM = &smem[M_OFF + (wc * 32 + r15) * 32 + ps];
    const u16* pP = &smem[P_OFF + (wc * 32 + r15) * 32 + ps];

    // staging: one gload16 round covers a full 128x32 tile (512 thr x 16B)
    int srow = tid >> 2, sq = tid & 3;
    int qsw = (sq ^ (srow & 3) ^ ((srow >> 2) & 3)) << 3;
    auto stA = [&](int buf, int ks) {
        gload16(Abase + (size_t)srow * KH + ks * 32 + qsw,
                &smem[A_OFF + buf * 4096 + srow * 32 + sq * 8]);
    };
    auto stM = [&](int buf, int ks) {
        gload16(Mbase + (size_t)srow * KH + ks * 32 + qsw,
                &smem[M_OFF + buf * 4096 + srow * 32 + sq * 8]);
    };
    auto stP = [&](int buf, int ks) {
        gload16(Pbase + (size_t)srow * KH + ks * 32 + qsw,
                &smem[P_OFF + buf * 4096 + srow * 32 + sq * 8]);
    };

    f32x4 accM[4][2], accP[4][2];
    #pragma unroll
    for (int i = 0; i < 4; ++i)
        #pragma unroll
        for (int j = 0; j < 2; ++j) { accM[i][j] = 0.0f; accP[i][j] = 0.0f; }

    s16x8 af[4], fm[2], fp[2];

    // ---- prologue: stage K0 into buf0 ----
    stA(0, 0); stM(0, 0); stP(0, 0);
    WAITV(0); BAR();

    // ---- steady loop: K-steps 0..14 (16 total, BK=32) ----
    for (int t = 0; t < 14; t += 2) {
        STEP(0, t)
        STEP(1, t + 1)
    }
    STEP(0, 14)     // stages ks=15 into buf1

    // ---- K-step 15: compute only (cur = 1) ----
    {
        RDA(1) RDM(1)
        PRIO1 MMAM PRIO0
        RDP(1)
        PRIO1 MMAP PRIO0
    }

    // ---- epilogue phase 1: bias + user fold + fast sigmoid -> LDS tile ----
    BAR();   // all waves done reading K-loop LDS; reuse pool as tile [128][TST]
    {
        int gc0 = nt * 128 + wc * 32 + r15;
        int gc1 = gc0 + 16;
        int bix = mt >> 2;                  // 4 blocks of 128 rows per batch
        size_t ub = ((size_t)a * NB + bix) * ND;
        float bmv0 = bm[a * ND + gc0] + uM[ub + gc0];
        float bmv1 = bm[a * ND + gc1] + uM[ub + gc1];
        float bpv0 = bp[a * ND + gc0] + uP[ub + gc0];
        float bpv1 = bp[a * ND + gc1] + uP[ub + gc1];
        int col0 = wc * 32 + r15;
        #pragma unroll
        for (int i = 0; i < 4; ++i) {
            int row0 = wr * 64 + i * 16 + g * 4;
            #pragma unroll
            for (int jj = 0; jj < 4; ++jj) {
                float m0 = accM[i][0][jj] + bmv0;
                float p0 = accP[i][0][jj] + bpv0;
                float v0 = p0 * __builtin_amdgcn_rcpf(1.0f + __expf(-m0));
                float m1 = accM[i][1][jj] + bmv1;
                float p1 = accP[i][1][jj] + bpv1;
                float v1 = p1 * __builtin_amdgcn_rcpf(1.0f + __expf(-m1));
                unsigned int pk;
                asm("v_cvt_pk_bf16_f32 %0, %1, %2" : "=v"(pk) : "v"(v0), "v"(v1));
                smem[(row0 + jj) * TST + col0]      = (u16)pk;
                smem[(row0 + jj) * TST + col0 + 16] = (u16)(pk >> 16);
            }
        }
    }
    BAR();
    // ---- epilogue phase 2: coalesced item store + fused score partials ----
    {
        #pragma unroll
        for (int q = 0; q < 4; ++q) {
            int cid = q * 512 + tid;            // 128 rows x 16 chunks
            int row_l = cid >> 4;
            int c8 = (cid & 15) << 3;
            u16x8 tv = *(const u16x8*)&smem[row_l * TST + c8];
            int rowg = mt * 128 + row_l;
            int a2 = rowg & 7;
            int colg8 = nt * 128 + c8;
            f32x4 w0 = *(const f32x4*)&asp[a2 * ND + colg8];
            f32x4 w1 = *(const f32x4*)&asp[a2 * ND + colg8 + 4];
            float s = b2f(tv[0]) * w0[0] + b2f(tv[1]) * w0[1]
                    + b2f(tv[2]) * w0[2] + b2f(tv[3]) * w0[3]
                    + b2f(tv[4]) * w1[0] + b2f(tv[5]) * w1[1]
                    + b2f(tv[6]) * w1[2] + b2f(tv[7]) * w1[3];
            *(u16x8*)(item + ((size_t)al * MROWS + rowg) * ND + colg8) = tv;
            s += __shfl_xor(s, 1);
            s += __shfl_xor(s, 2);
            s += __shfl_xor(s, 4);
            s += __shfl_xor(s, 8);
            if ((tid & 15) == 0)
                scorep[((size_t)al * MROWS + rowg) * 4 + nt] = s;
        }
    }
}

// ---------------- kernel 4: softmax(L) + weighted sum, D-split x8 ----------------
// grid = n*512: block = (bl, ap, ds); each block owns 64 output columns.
// Wave-shuffle softmax reductions (3 barriers instead of ~18).
__global__ __launch_bounds__(512) void attn_out_k(
    const u16* __restrict__ item, const float* __restrict__ scorep,
    float* __restrict__ out, int b0) {
    __shared__ float attn[512];
    __shared__ float red[512];
    __shared__ float wred[8];
    int t = threadIdx.x;
    int lane = t & 63, wid = t >> 6;
    int ds = blockIdx.x & 7;              // D slice (64 cols)
    int ap = (blockIdx.x >> 3) & 7;       // aspect slot
    int bl = blockIdx.x >> 6;             // local batch
    int bg = b0 + bl;

    // scores: thread t owns l'=t
    size_t R = (size_t)bl * 4096 + (size_t)t * 8 + ap;
    f32x4 q = *(const f32x4*)(scorep + R * 4);
    float s = (q[0] + q[1]) + (q[2] + q[3]);

    // wave-level max reduce, then cross-wave via 8-slot LDS
    float m = s;
    #pragma unroll
    for (int off = 32; off > 0; off >>= 1) m = fmaxf(m, __shfl_xor(m, off));
    if (lane == 0) wred[wid] = m;
    __syncthreads();
    float mx = wred[0];
    #pragma unroll
    for (int k = 1; k < 8; ++k) mx = fmaxf(mx, wred[k]);
    float p = __expf(s - mx);
    float su = p;
    #pragma unroll
    for (int off = 32; off > 0; off >>= 1) su += __shfl_xor(su, off);
    __syncthreads();        // wred reuse WAR
    if (lane == 0) wred[wid] = su;
    __syncthreads();
    float tot = wred[0] + wred[1] + wred[2] + wred[3]
              + wred[4] + wred[5] + wred[6] + wred[7];
    attn[t] = p * (1.0f / tot);
    __syncthreads();

    // weighted sum over this block's 64 columns; 8 l-groups x 64 cols
    int lg = t >> 6, c = t & 63;
    const u16* base = item + ((size_t)bl * 4096 + ap) * ND + ds * 64 + c;
    float acc = 0.0f;
    #pragma unroll 4
    for (int l = lg; l < 512; l += 8)
        acc += attn[l] * b2f(base[(size_t)l * 8 * ND]);
    red[t] = acc;
    __syncthreads();
    if (t < 64) {
        float o = 0.0f;
        #pragma unroll
        for (int k = 0; k < 8; ++k) o += red[k * 64 + t];
        out[((size_t)bg * NA + ap) * ND + ds * 64 + t] = o;
    }
}

// ---------------- launcher ----------------
extern "C" void kernel_launch(void* const* d_in, const int* in_sizes, int n_in,
                              void* d_out, int out_size, void* d_ws, size_t ws_size,
                              hipStream_t stream) {
    const float* H   = (const float*)d_in[0];
    const float* U   = (const float*)d_in[1];
    const float* asp = (const float*)d_in[2];
    const float* Wmf = (const float*)d_in[3];
    const float* bmf = (const float*)d_in[4];
    const float* Wpf = (const float*)d_in[5];
    const float* bpf = (const float*)d_in[6];
    float* out = (float*)d_out;

    char* ws = (char*)d_ws;
    const size_t BT_BYTES = (size_t)MROWS * KH * 2;            // 32 MB
    const size_t WT_BYTES = (size_t)NA * ND * KH * 2;          // 4 MB each
    const size_t U_BYTES  = (size_t)NA * NB * ND * 4;          // 1 MB each
    u16*   Bt = (u16*)(ws);
    u16*   Wm = (u16*)(ws + BT_BYTES);
    u16*   Wp = (u16*)(ws + BT_BYTES + WT_BYTES);
    float* uM = (float*)(ws + BT_BYTES + 2 * WT_BYTES);
    float* uP = (float*)(ws + BT_BYTES + 2 * WT_BYTES + U_BYTES);
    size_t fixed = BT_BYTES + 2 * WT_BYTES + 2 * U_BYTES;      // 42 MB
    const size_t ITEM_PER_ASPECT  = (size_t)MROWS * ND * 2;    // 32 MB
    const size_t SCORE_PER_ASPECT = (size_t)MROWS * 4 * 4;     // 512 KB
    size_t avail = (ws_size > fixed) ? (ws_size - fixed) : 0;
    int na = (int)(avail / (ITEM_PER_ASPECT + SCORE_PER_ASPECT));
    if (na > NA) na = NA;
    if (na < 1) na = 1;
    int log2na = 0;
    while ((2 << log2na) <= na) ++log2na;
    na = 1 << log2na;
    u16*   item   = (u16*)(ws + fixed);
    float* scorep = (float*)(ws + fixed + (size_t)na * ITEM_PER_ASPECT);

    prep_k<<<PREP_BB + PREP_WT + PREP_UM, 256, 0, stream>>>(
        H, Bt, Wmf, Wpf, Wm, Wp, U, uM, uP);

    for (int a0 = 0; a0 < NA; a0 += na) {
        int n = (na < NA - a0) ? na : (NA - a0);
        gemm8_k<<<n * 1024, 512, 0, stream>>>(Bt, Wm, Wp, bmf, bpf, uM, uP, asp,
                                              item, scorep, a0, log2na, n * 1024);
        attn_out_k<<<n * 512, 512, 0, stream>>>(item, scorep, out, a0 * 8);
    }
}

// Round 17
// 418.767 us; speedup vs baseline: 2.3754x; 1.0081x over previous
//
#include <hip/hip_runtime.h>
#include <hip/hip_bf16.h>

// ---------------- types ----------------
typedef unsigned short u16;
typedef u16   u16x4 __attribute__((ext_vector_type(4)));
typedef u16   u16x8 __attribute__((ext_vector_type(8)));
typedef short s16x8 __attribute__((ext_vector_type(8)));
typedef float f32x4 __attribute__((ext_vector_type(4)));

// Problem constants
#define NB   64
#define NL   512
#define ND   512
#define NA   8
#define K2   1024        // 2*D (original concat K)
#define KH   512         // GEMM K after user-split (H part only)
#define MROWS 32768      // B*L

__device__ __forceinline__ float b2f(u16 u) {
    unsigned int x = ((unsigned int)u) << 16;
    return __uint_as_float(x);
}
__device__ __forceinline__ u16 f2b(float f) {
    unsigned int x = __float_as_uint(f);
    unsigned int r = (x + 0x7fffu + ((x >> 16) & 1u)) >> 16;
    return (u16)r;
}

// permuted column position for original k within a 64-col K-block (16x16x32 frag)
__device__ __forceinline__ int permc(int k) {
    int ks  = k >> 6;
    int kr  = k & 63;
    int kk  = kr >> 5;
    int k32 = kr & 31;
    int h   = k32 >> 4;
    int rem = k32 & 15;
    int g   = rem >> 2;
    int e0  = rem & 3;
    return ks * 64 + kk * 32 + g * 8 + h * 4 + e0;
}

__device__ __forceinline__ void gload16(const u16* g, u16* l) {
    __builtin_amdgcn_global_load_lds(
        (const __attribute__((address_space(1))) unsigned int*)g,
        (__attribute__((address_space(3))) unsigned int*)l, 16, 0, 0);
}

// ---------------- kernel 1: fused prep (build_batch + build_wt + user_mm) ----------------
#define PREP_BB 4096
#define PREP_WT 2048
#define PREP_UM 512

__global__ __launch_bounds__(256) void prep_k(
    const float* __restrict__ H, u16* __restrict__ Bt,
    const float* __restrict__ Wmf, const float* __restrict__ Wpf,
    u16* __restrict__ Wm, u16* __restrict__ Wp,
    const float* __restrict__ U, float* __restrict__ uM, float* __restrict__ uP) {
    __shared__ float shp[5120];     // 20 KB union
    int bid = blockIdx.x;
    int t = threadIdx.x;

    if (bid < PREP_BB) {
        // ---- build_batch ----
        size_t stride = (size_t)PREP_BB * 256;
        for (size_t idx = (size_t)bid * 256 + t; idx < (size_t)MROWS * 128; idx += stride) {
            int r  = (int)(idx >> 7);
            int c  = ((int)idx & 127) << 2;       // permuted col (multiple of 4)
            int ks = c >> 6;
            int w64 = c & 63;
            int cq = w64 >> 3;
            int h  = (w64 >> 2) & 1;
            int kbase = ks * 64 + (cq >> 2) * 32 + (cq & 3) * 4 + h * 16;  // < 512
            f32x4 v = *(const f32x4*)(H + (size_t)r * ND + kbase);
            u16x4 o;
            o[0] = f2b(v[0]); o[1] = f2b(v[1]); o[2] = f2b(v[2]); o[3] = f2b(v[3]);
            *(u16x4*)(Bt + (size_t)r * KH + c) = o;
        }
    } else if (bid < PREP_BB + PREP_WT) {
        // ---- build_wt ----
        int b2 = bid - PREP_BB;
        float (*ld)[65] = (float(*)[65])shp;
        int kt  = b2 & 15;
        int dt  = (b2 >> 4) & 7;
        int a   = (b2 >> 7) & 7;
        int mat = b2 >> 10;
        const float* W = mat ? Wpf : Wmf;
        u16* Wt = mat ? Wp : Wm;
        int k0 = kt * 32, d0 = dt * 64;
        #pragma unroll
        for (int it = 0; it < 8; ++it) {
            int lin = it * 256 + t;
            int i = lin >> 6, j = lin & 63;
            ld[i][j] = W[((size_t)a * K2 + k0 + i) * ND + d0 + j];
        }
        __syncthreads();
        #pragma unroll
        for (int it = 0; it < 8; ++it) {
            int lin = it * 256 + t;
            int dl = lin >> 5, kl = lin & 31;
            int k = k0 + kl;
            Wt[((size_t)a * ND + d0 + dl) * KH + permc(k)] = f2b(ld[kl][dl]);
        }
    } else {
        // ---- user_mm: block = (a, mat, cg of 64 cols, bs of 16 batches) ----
        int b2 = bid - PREP_BB - PREP_WT;
        int a   = b2 & 7;
        int mat = (b2 >> 3) & 1;
        int cg  = (b2 >> 4) & 7;
        int bs  = b2 >> 7;               // 0..3
        const float* W = mat ? Wpf : Wmf;
        float* uX = mat ? uP : uM;
        float* ul = shp;                 // [16][64]
        float* wl = shp + 1024;          // [64][64]
        int c = t & 63, bq = t >> 6;     // col, batch-quarter (wave-uniform)

        float acc[4] = {0.0f, 0.0f, 0.0f, 0.0f};
        for (int kt = 0; kt < 8; ++kt) {
            __syncthreads();
            #pragma unroll
            for (int it = 0; it < 16; ++it) {
                int idx = it * 256 + t;
                wl[idx] = W[((size_t)a * K2 + 512 + kt * 64 + (idx >> 6)) * ND + cg * 64 + (idx & 63)];
            }
            #pragma unroll
            for (int it = 0; it < 4; ++it) {
                int idx = it * 256 + t;
                ul[idx] = U[(size_t)(bs * 16 + (idx >> 6)) * ND + kt * 64 + (idx & 63)];
            }
            __syncthreads();
            #pragma unroll
            for (int k4 = 0; k4 < 16; ++k4) {
                f32x4 uv[4];
                #pragma unroll
                for (int bi = 0; bi < 4; ++bi)
                    uv[bi] = *(const f32x4*)&ul[(bq * 4 + bi) * 64 + k4 * 4];  // broadcast read
                #pragma unroll
                for (int e = 0; e < 4; ++e) {
                    float wv = wl[(k4 * 4 + e) * 64 + c];                      // conflict-free
                    #pragma unroll
                    for (int bi = 0; bi < 4; ++bi)
                        acc[bi] += uv[bi][e] * wv;
                }
            }
        }
        #pragma unroll
        for (int bi = 0; bi < 4; ++bi)
            uX[((size_t)a * NB + bs * 16 + bq * 4 + bi) * ND + cg * 64 + c] = acc[bi];
    }
}

// ---------------- kernel 3: 128x128-tile K=512 dual GEMM, 2 blocks/CU ----------------
// BM=128, BN=128, BK=32, 8 waves (2M x 4N, wave 64x32), double-buffered LDS 48KB.
// LDS row-pairing: two M-rows per 128B LDS row + 8-slot XOR swizzle -> 2-way (free).
#define BAR()    do { __builtin_amdgcn_sched_barrier(0); \
                      __builtin_amdgcn_s_barrier(); \
                      __builtin_amdgcn_sched_barrier(0); } while (0)
#define WAITV(n) do { asm volatile("s_waitcnt vmcnt(" #n ")" ::: "memory"); \
                      __builtin_amdgcn_sched_barrier(0); } while (0)
#define PRIO1    __builtin_amdgcn_s_setprio(1);
#define PRIO0    __builtin_amdgcn_s_setprio(0);

// LDS pool (u16 units): A 2x4096 @0, Bm 2x4096 @8192, Bp 2x4096 @16384.
// Each 4096-u16 buffer = 64 pair-rows x 64 u16 (128B).
#define A_OFF  0
#define M_OFF  8192
#define P_OFF  16384
#define TST    136      // epilogue tile row stride (u16), 128x136 = 34KB

#define RDA(B_) { _Pragma("unroll") for (int i_ = 0; i_ < 4; ++i_) \
    af[i_] = *(const s16x8*)(pA + (B_) * 4096 + i_ * 512); }
#define RDM(B_) { fm[0] = *(const s16x8*)(pM + (B_) * 4096); \
                  fm[1] = *(const s16x8*)(pM + (B_) * 4096 + 512); }
#define RDP(B_) { fp[0] = *(const s16x8*)(pP + (B_) * 4096); \
                  fp[1] = *(const s16x8*)(pP + (B_) * 4096 + 512); }

#define MMAM { _Pragma("unroll") for (int i_ = 0; i_ < 4; ++i_) \
    _Pragma("unroll") for (int j_ = 0; j_ < 2; ++j_) \
        accM[i_][j_] = __builtin_amdgcn_mfma_f32_16x16x32_bf16( \
            af[i_], fm[j_], accM[i_][j_], 0, 0, 0); }
#define MMAP { _Pragma("unroll") for (int i_ = 0; i_ < 4; ++i_) \
    _Pragma("unroll") for (int j_ = 0; j_ < 2; ++j_) \
        accP[i_][j_] = __builtin_amdgcn_mfma_f32_16x16x32_bf16( \
            af[i_], fp[j_], accP[i_][j_], 0, 0, 0); }

#define STEP(CUR, T) { \
    stA((CUR) ^ 1, (T) + 1); stM((CUR) ^ 1, (T) + 1); stP((CUR) ^ 1, (T) + 1); \
    RDA(CUR) RDM(CUR) \
    PRIO1 MMAM PRIO0 \
    RDP(CUR) \
    PRIO1 MMAP PRIO0 \
    WAITV(0); BAR(); }

__global__ __launch_bounds__(512, 4) void gemm8_k(
    const u16* __restrict__ Bt, const u16* __restrict__ Wm, const u16* __restrict__ Wp,
    const float* __restrict__ bm, const float* __restrict__ bp,
    const float* __restrict__ uM, const float* __restrict__ uP,
    const float* __restrict__ asp,
    u16* __restrict__ item, float* __restrict__ scorep,
    int a0, int log2na, int nwg) {
    __shared__ u16 smem[24576];         // 48 KB pool

    int bid = blockIdx.x;
    int chunk = nwg >> 3;                       // XCD-aware swizzle (nwg % 8 == 0)
    int b = (bid & 7) * chunk + (bid >> 3);
    int nt = b & 3;                             // N-tile fastest: share A panel
    int al = (b >> 2) & ((1 << log2na) - 1);
    int mt = b >> (2 + log2na);                 // 0..255
    int a  = a0 + al;

    int tid = threadIdx.x;
    int lane = tid & 63;
    int w  = tid >> 6;        // 0..7
    int wr = w >> 2;          // 0..1  (M half: 64 rows)
    int wc = w & 3;           // 0..3  (N quarter: 32 cols)
    int g = lane >> 4, r15 = lane & 15;

    const u16* Abase = Bt + (size_t)(mt * 128) * KH;
    const u16* Mbase = Wm + ((size_t)a * ND + nt * 128) * KH;
    const u16* Pbase = Wp + ((size_t)a * ND + nt * 128) * KH;

    // ---- hoisted pair-row swizzled read bases ----
    // logical row r -> pair rp=r>>1, slot = ((r&1)*4+g) ^ (rp&7); both loop-invariant:
    // r&1 = r15&1, rp&7 = (r15>>1)&7 for all i/j blocks (i*8, j*8 are 0 mod 8).
    int sA = ((((r15 & 1) << 2) + g) ^ ((r15 >> 1) & 7)) << 3;   // u16 offset in pair-row
    const u16* pA = &smem[A_OFF + (wr * 32 + (r15 >> 1)) * 64 + sA];
    const u16* pM = &smem[M_OFF + (wc * 16 + (r15 >> 1)) * 64 + sA];
    const u16* pP = &smem[P_OFF + (wc * 16 + (r15 >> 1)) * 64 + sA];

    // ---- staging: linear LDS dest (tid*16B), inverse-permuted global source ----
    // dest pair-row p = tid>>3, dest slot = tid&7; logical slot_l = slot ^ (p&7);
    // src row = 2p + (slot_l>>2), src k-offset = (slot_l&3)*8.
    int prow = tid >> 3;
    int sl_l = (tid & 7) ^ (prow & 7);
    int srcr = prow * 2 + (sl_l >> 2);
    int srck = (sl_l & 3) << 3;
    auto stA = [&](int buf, int ks) {
        gload16(Abase + (size_t)srcr * KH + ks * 32 + srck,
                &smem[A_OFF + buf * 4096 + tid * 8]);
    };
    auto stM = [&](int buf, int ks) {
        gload16(Mbase + (size_t)srcr * KH + ks * 32 + srck,
                &smem[M_OFF + buf * 4096 + tid * 8]);
    };
    auto stP = [&](int buf, int ks) {
        gload16(Pbase + (size_t)srcr * KH + ks * 32 + srck,
                &smem[P_OFF + buf * 4096 + tid * 8]);
    };

    f32x4 accM[4][2], accP[4][2];
    #pragma unroll
    for (int i = 0; i < 4; ++i)
        #pragma unroll
        for (int j = 0; j < 2; ++j) { accM[i][j] = 0.0f; accP[i][j] = 0.0f; }

    s16x8 af[4], fm[2], fp[2];

    // ---- prologue: stage K0 into buf0 ----
    stA(0, 0); stM(0, 0); stP(0, 0);
    WAITV(0); BAR();

    // ---- steady loop: K-steps 0..14 (16 total, BK=32) ----
    for (int t = 0; t < 14; t += 2) {
        STEP(0, t)
        STEP(1, t + 1)
    }
    STEP(0, 14)     // stages ks=15 into buf1

    // ---- K-step 15: compute only (cur = 1) ----
    {
        RDA(1) RDM(1)
        PRIO1 MMAM PRIO0
        RDP(1)
        PRIO1 MMAP PRIO0
    }

    // ---- epilogue phase 1: bias + user fold + fast sigmoid -> LDS tile ----
    BAR();   // all waves done reading K-loop LDS; reuse pool as tile [128][TST]
    {
        int gc0 = nt * 128 + wc * 32 + r15;
        int gc1 = gc0 + 16;
        int bix = mt >> 2;                  // 4 blocks of 128 rows per batch
        size_t ub = ((size_t)a * NB + bix) * ND;
        float bmv0 = bm[a * ND + gc0] + uM[ub + gc0];
        float bmv1 = bm[a * ND + gc1] + uM[ub + gc1];
        float bpv0 = bp[a * ND + gc0] + uP[ub + gc0];
        float bpv1 = bp[a * ND + gc1] + uP[ub + gc1];
        int col0 = wc * 32 + r15;
        #pragma unroll
        for (int i = 0; i < 4; ++i) {
            int row0 = wr * 64 + i * 16 + g * 4;
            #pragma unroll
            for (int jj = 0; jj < 4; ++jj) {
                float m0 = accM[i][0][jj] + bmv0;
                float p0 = accP[i][0][jj] + bpv0;
                float v0 = p0 * __builtin_amdgcn_rcpf(1.0f + __expf(-m0));
                float m1 = accM[i][1][jj] + bmv1;
                float p1 = accP[i][1][jj] + bpv1;
                float v1 = p1 * __builtin_amdgcn_rcpf(1.0f + __expf(-m1));
                unsigned int pk;
                asm("v_cvt_pk_bf16_f32 %0, %1, %2" : "=v"(pk) : "v"(v0), "v"(v1));
                smem[(row0 + jj) * TST + col0]      = (u16)pk;
                smem[(row0 + jj) * TST + col0 + 16] = (u16)(pk >> 16);
            }
        }
    }
    BAR();
    // ---- epilogue phase 2: coalesced item store + fused score partials ----
    {
        #pragma unroll
        for (int q = 0; q < 4; ++q) {
            int cid = q * 512 + tid;            // 128 rows x 16 chunks
            int row_l = cid >> 4;
            int c8 = (cid & 15) << 3;
            u16x8 tv = *(const u16x8*)&smem[row_l * TST + c8];
            int rowg = mt * 128 + row_l;
            int a2 = rowg & 7;
            int colg8 = nt * 128 + c8;
            f32x4 w0 = *(const f32x4*)&asp[a2 * ND + colg8];
            f32x4 w1 = *(const f32x4*)&asp[a2 * ND + colg8 + 4];
            float s = b2f(tv[0]) * w0[0] + b2f(tv[1]) * w0[1]
                    + b2f(tv[2]) * w0[2] + b2f(tv[3]) * w0[3]
                    + b2f(tv[4]) * w1[0] + b2f(tv[5]) * w1[1]
                    + b2f(tv[6]) * w1[2] + b2f(tv[7]) * w1[3];
            *(u16x8*)(item + ((size_t)al * MROWS + rowg) * ND + colg8) = tv;
            s += __shfl_xor(s, 1);
            s += __shfl_xor(s, 2);
            s += __shfl_xor(s, 4);
            s += __shfl_xor(s, 8);
            if ((tid & 15) == 0)
                scorep[((size_t)al * MROWS + rowg) * 4 + nt] = s;
        }
    }
}

// ---------------- kernel 4: softmax(L) + weighted sum, D-split x8 ----------------
__global__ __launch_bounds__(512) void attn_out_k(
    const u16* __restrict__ item, const float* __restrict__ scorep,
    float* __restrict__ out, int b0) {
    __shared__ float attn[512];
    __shared__ float red[512];
    __shared__ float wred[8];
    int t = threadIdx.x;
    int lane = t & 63, wid = t >> 6;
    int ds = blockIdx.x & 7;              // D slice (64 cols)
    int ap = (blockIdx.x >> 3) & 7;       // aspect slot
    int bl = blockIdx.x >> 6;             // local batch
    int bg = b0 + bl;

    size_t R = (size_t)bl * 4096 + (size_t)t * 8 + ap;
    f32x4 q = *(const f32x4*)(scorep + R * 4);
    float s = (q[0] + q[1]) + (q[2] + q[3]);

    float m = s;
    #pragma unroll
    for (int off = 32; off > 0; off >>= 1) m = fmaxf(m, __shfl_xor(m, off));
    if (lane == 0) wred[wid] = m;
    __syncthreads();
    float mx = wred[0];
    #pragma unroll
    for (int k = 1; k < 8; ++k) mx = fmaxf(mx, wred[k]);
    float p = __expf(s - mx);
    float su = p;
    #pragma unroll
    for (int off = 32; off > 0; off >>= 1) su += __shfl_xor(su, off);
    __syncthreads();        // wred reuse WAR
    if (lane == 0) wred[wid] = su;
    __syncthreads();
    float tot = wred[0] + wred[1] + wred[2] + wred[3]
              + wred[4] + wred[5] + wred[6] + wred[7];
    attn[t] = p * (1.0f / tot);
    __syncthreads();

    int lg = t >> 6, c = t & 63;
    const u16* base = item + ((size_t)bl * 4096 + ap) * ND + ds * 64 + c;
    float acc = 0.0f;
    #pragma unroll 4
    for (int l = lg; l < 512; l += 8)
        acc += attn[l] * b2f(base[(size_t)l * 8 * ND]);
    red[t] = acc;
    __syncthreads();
    if (t < 64) {
        float o = 0.0f;
        #pragma unroll
        for (int k = 0; k < 8; ++k) o += red[k * 64 + t];
        out[((size_t)bg * NA + ap) * ND + ds * 64 + t] = o;
    }
}

// ---------------- launcher ----------------
extern "C" void kernel_launch(void* const* d_in, const int* in_sizes, int n_in,
                              void* d_out, int out_size, void* d_ws, size_t ws_size,
                              hipStream_t stream) {
    const float* H   = (const float*)d_in[0];
    const float* U   = (const float*)d_in[1];
    const float* asp = (const float*)d_in[2];
    const float* Wmf = (const float*)d_in[3];
    const float* bmf = (const float*)d_in[4];
    const float* Wpf = (const float*)d_in[5];
    const float* bpf = (const float*)d_in[6];
    float* out = (float*)d_out;

    char* ws = (char*)d_ws;
    const size_t BT_BYTES = (size_t)MROWS * KH * 2;            // 32 MB
    const size_t WT_BYTES = (size_t)NA * ND * KH * 2;          // 4 MB each
    const size_t U_BYTES  = (size_t)NA * NB * ND * 4;          // 1 MB each
    u16*   Bt = (u16*)(ws);
    u16*   Wm = (u16*)(ws + BT_BYTES);
    u16*   Wp = (u16*)(ws + BT_BYTES + WT_BYTES);
    float* uM = (float*)(ws + BT_BYTES + 2 * WT_BYTES);
    float* uP = (float*)(ws + BT_BYTES + 2 * WT_BYTES + U_BYTES);
    size_t fixed = BT_BYTES + 2 * WT_BYTES + 2 * U_BYTES;      // 42 MB
    const size_t ITEM_PER_ASPECT  = (size_t)MROWS * ND * 2;    // 32 MB
    const size_t SCORE_PER_ASPECT = (size_t)MROWS * 4 * 4;     // 512 KB
    size_t avail = (ws_size > fixed) ? (ws_size - fixed) : 0;
    int na = (int)(avail / (ITEM_PER_ASPECT + SCORE_PER_ASPECT));
    if (na > NA) na = NA;
    if (na < 1) na = 1;
    int log2na = 0;
    while ((2 << log2na) <= na) ++log2na;
    na = 1 << log2na;
    u16*   item   = (u16*)(ws + fixed);
    float* scorep = (float*)(ws + fixed + (size_t)na * ITEM_PER_ASPECT);

    prep_k<<<PREP_BB + PREP_WT + PREP_UM, 256, 0, stream>>>(
        H, Bt, Wmf, Wpf, Wm, Wp, U, uM, uP);

    for (int a0 = 0; a0 < NA; a0 += na) {
        int n = (na < NA - a0) ? na : (NA - a0);
        gemm8_k<<<n * 1024, 512, 0, stream>>>(Bt, Wm, Wp, bmf, bpf, uM, uP, asp,
                                              item, scorep, a0, log2na, n * 1024);
        attn_out_k<<<n * 512, 512, 0, stream>>>(item, scorep, out, a0 * 8);
    }
}